// Round 6
// baseline (209.258 us; speedup 1.0000x reference)
//
#include <hip/hip_runtime.h>
#include <cstdint>
#include <cstddef>

using bf16x8 = __attribute__((ext_vector_type(8))) short;
using f32x4  = __attribute__((ext_vector_type(4))) float;

__device__ __forceinline__ unsigned short f2bf(float f) {
  unsigned int u = __builtin_bit_cast(unsigned int, f);
  u += 0x7FFFu + ((u >> 16) & 1u);   // round-to-nearest-even
  return (unsigned short)(u >> 16);
}
__device__ __forceinline__ float bf2f(unsigned int h16) {
  unsigned int u = h16 << 16;
  return __builtin_bit_cast(float, u);
}

__device__ __forceinline__ void gl_lds16(const void* g, void* l) {
  __builtin_amdgcn_global_load_lds(
      (const __attribute__((address_space(1))) unsigned int*)g,
      (__attribute__((address_space(3))) unsigned int*)l,
      16, 0, 0);
}

#define MFMA  __builtin_amdgcn_mfma_f32_16x16x32_bf16
#define MFMA8 __builtin_amdgcn_mfma_f32_16x16x32_fp8_fp8

// ============ fp8 E-kernel: E[m,n]=exp(scale/(dist+0.1)), denom atomics ====
// Rounds 0-5 all ran at Occupancy ~20% (64KB LDS -> 2 blocks/CU, 2 waves/SIMD)
// and every convoy rearrangement was null: the lever is CONCURRENCY.
// This version: BK=64 fp8 -> 8KB slots, 32KB staging (34.8KB total with the
// epilogue transpose tile) -> 4 blocks/CU, grid 2048 = 8/CU at 4-deep.
// 64-B rows = 4 chunks of 16B; chunk-XOR s(r)=(r>>2)&3: LDS slot q of row r
// holds global chunk q^s(r). ds_read_b64 bank spread is even (<=2-way within
// a quad group, disjoint bank pairs across quads).
__global__ __launch_bounds__(256, 4)
void gemm_f8(const unsigned char* __restrict__ A,   // [8192][512] fp8 e4m3
             const unsigned char* __restrict__ B,   // [4096][512] fp8 e4m3
             unsigned short* __restrict__ Eg,       // [8192][4096] bf16
             const float* __restrict__ x2g,
             const float* __restrict__ p2g,
             const float* __restrict__ scg,
             float* __restrict__ denom)
{
  constexpr int K = 512, N = 4096;
  constexpr int ASZ = 128 * 64;               // bytes per slot (8 KB)
  __shared__ unsigned char smem[34816];       // staging 32 KB; epilogue 128x136x2
  unsigned char* As = smem;                   // A slots 0,1
  unsigned char* Bs = smem + 2 * ASZ;         // B slots 0,1

  const int tid  = threadIdx.x;
  const int lane = tid & 63;
  const int wv   = tid >> 6;
  const int wm   = (wv >> 1) * 64;
  const int wn   = (wv & 1) * 64;
  const int l16  = lane & 15;
  const int quad = lane >> 4;

  // 2048 blocks: XCD owns a 4-wide n-band (p-slice L2-resident per XCD)
  const int lin = blockIdx.x;
  const int xcd = lin & 7, per = lin >> 3;
  const int xt = xcd * 4 + (per & 3), yt = per >> 2;
  const int n0 = xt * 128, m0 = yt * 128;

  f32x4 acc[4][4];
#pragma unroll
  for (int i = 0; i < 4; ++i)
#pragma unroll
    for (int j = 0; j < 4; ++j) {
      f32x4 z = {0.f, 0.f, 0.f, 0.f};
      acc[i][j] = z;
    }

  // staging: c = tid + i*256 in [0,512): row=c>>2, slot q=c&3,
  // global chunk = q ^ ((row>>2)&3)
  const unsigned char* gA[2]; const unsigned char* gB[2]; int lA[2];
#pragma unroll
  for (int i = 0; i < 2; ++i) {
    const int c = tid + i * 256;
    const int row = c >> 2;
    const int colb = ((c & 3) ^ ((row >> 2) & 3)) * 16;
    gA[i] = A + (size_t)(m0 + row) * K + colb;
    gB[i] = B + (size_t)(n0 + row) * K + colb;
    lA[i] = c * 16;
  }

  auto issue = [&](int st, int kc) {
#pragma unroll
    for (int i = 0; i < 2; ++i) gl_lds16(gA[i] + kc, &As[st * ASZ + lA[i]]);
#pragma unroll
    for (int i = 0; i < 2; ++i) gl_lds16(gB[i] + kc, &Bs[st * ASZ + lA[i]]);
  };

  issue(0, 0);
  int cur = 0;
#pragma unroll 1
  for (int it = 0; it < 8; ++it) {            // BK=64, nk=8
    __builtin_amdgcn_s_barrier();
    if (it < 7) {
      issue(cur ^ 1, (it + 1) * 64);
      __builtin_amdgcn_s_waitcnt(0x0F74);     // my 4 landed; next 4 in flight
    } else {
      __builtin_amdgcn_s_waitcnt(0x0F70);
    }
    __builtin_amdgcn_s_barrier();

#pragma unroll
    for (int sub = 0; sub < 2; ++sub) {       // 2 x K=32 sub-steps
      long af[4], bq[4];
#pragma unroll
      for (int mi = 0; mi < 4; ++mi) {
        const int r = wm + mi * 16 + l16;
        af[mi] = *(const long*)&As[cur * ASZ + r * 64 +
                   (((sub * 2 + (quad >> 1)) ^ ((r >> 2) & 3)) * 16) + (quad & 1) * 8];
      }
#pragma unroll
      for (int ni = 0; ni < 4; ++ni) {
        const int r = wn + ni * 16 + l16;
        bq[ni] = *(const long*)&Bs[cur * ASZ + r * 64 +
                   (((sub * 2 + (quad >> 1)) ^ ((r >> 2) & 3)) * 16) + (quad & 1) * 8];
      }
#pragma unroll
      for (int mi = 0; mi < 4; ++mi)
#pragma unroll
        for (int ni = 0; ni < 4; ++ni)
          acc[mi][ni] = MFMA8(af[mi], bq[ni], acc[mi][ni], 0, 0, 0);
    }
    cur ^= 1;
  }

  // ---- epilogue (proven): exp into 136-stride LDS tile, row sums, stores ----
  float p2v[4], scv[4];
#pragma unroll
  for (int ni = 0; ni < 4; ++ni) {
    const int n = n0 + wn + ni * 16 + l16;
    p2v[ni] = p2g[n];
    scv[ni] = scg[n] * 1.44269504088896f;     // fold log2(e)
  }
  __syncthreads();                            // done with K-loop LDS
  unsigned short* Es = (unsigned short*)smem; // 128 x (136-stride) bf16 tile
#pragma unroll
  for (int mi = 0; mi < 4; ++mi) {
#pragma unroll
    for (int r = 0; r < 4; ++r) {
      const int rowL = wm + mi * 16 + quad * 4 + r;
      const float rowa = x2g[m0 + rowL];
      float s = 0.f;
#pragma unroll
      for (int ni = 0; ni < 4; ++ni) {
        const int col = wn + ni * 16 + l16;
        const float v = acc[mi][ni][r];
        float sq   = fmaxf(rowa - 2.0f * v + p2v[ni], 0.0f);
        float dist = __builtin_amdgcn_sqrtf(sq);
        float e    = __builtin_amdgcn_exp2f(scv[ni] * __builtin_amdgcn_rcpf(dist + 0.1f));
        Es[rowL * 136 + col] = f2bf(e);
        s += e;                               // unrounded sum (rel err ~3e-5)
      }
      s += __shfl_down(s, 8);
      s += __shfl_down(s, 4);
      s += __shfl_down(s, 2);
      s += __shfl_down(s, 1);
      if (l16 == 0) unsafeAtomicAdd(&denom[m0 + rowL], s);
    }
  }
  __syncthreads();
#pragma unroll
  for (int j = 0; j < 8; ++j) {               // coalesced 16B stores
    const int cid = j * 256 + tid;
    const int row = cid >> 4, cc = cid & 15;
    bf16x8 v = *(const bf16x8*)&Es[row * 136 + cc * 8];
    *(bf16x8*)&Eg[(size_t)(m0 + row) * N + n0 + cc * 8] = v;
  }
}

// ============ PV kernel: part[z][m,e] = sum_{n in half z} E[m,n] v2T[e,n] ===
// Same occupancy recipe: BM=128, BN(e)=64, BK=32 -> 24 KB LDS -> 4 blocks/CU.
// grid 1024 (64m x 8e x 2z), m-octet pinned per XCD (E rows L2-local; e-tiles
// sharing the same E rows run co-XCD). nk=64. 64-B rows, chunk-XOR s(r)=(r>>2)&3.
__global__ __launch_bounds__(256, 4)
void gemm_pv(const unsigned short* __restrict__ A,   // E: [8192][4096] bf16
             const unsigned short* __restrict__ B,   // v2T: [512][4096] bf16
             unsigned short* __restrict__ part)      // [2][8192][512] bf16
{
  constexpr int NCOL = 4096, KC = 2048;
  constexpr int ASZ = 128 * 32;   // shorts per A slot (8 KB)
  constexpr int BSZ = 64 * 32;    // shorts per B slot (4 KB)
  __shared__ unsigned short smem[2 * (ASZ + BSZ)];   // 24 KB
  unsigned short* As = smem;
  unsigned short* Bs = smem + 2 * ASZ;

  const int tid  = threadIdx.x;
  const int lane = tid & 63;
  const int wv   = tid >> 6;
  const int l16  = lane & 15;
  const int quad = lane >> 4;
  const int wm   = (wv >> 1) * 64;
  const int wn   = (wv & 1) * 32;

  const int lin = blockIdx.x;                 // 1024 blocks
  const int xcd = lin & 7, i = lin >> 3;      // i in [0,128)
  const int yt  = xcd * 8 + (i & 7);          // m-tile octet pinned to XCD
  const int combo = i >> 3;                   // 0..15
  const int et  = combo & 7;                  // e-tile
  const int zt  = combo >> 3;                 // K half
  const int m0  = yt * 128;
  const int e0  = et * 64;
  const int kbeg = zt * KC;

  f32x4 acc[4][2];
#pragma unroll
  for (int a = 0; a < 4; ++a)
#pragma unroll
    for (int b = 0; b < 2; ++b) {
      f32x4 z = {0.f, 0.f, 0.f, 0.f};
      acc[a][b] = z;
    }

  // A: c = tid + i*256 in [0,512): row=c>>2 (0..127), slot q=c&3
  // B: c = tid in [0,256): row=c>>2 (0..63)
  const unsigned short* gA[2]; int lA[2];
  const unsigned short* gB;    int lB;
#pragma unroll
  for (int j = 0; j < 2; ++j) {
    const int c = tid + j * 256;
    const int row = c >> 2;
    const int col = ((c & 3) ^ ((row >> 2) & 3)) * 8;   // shorts
    gA[j] = A + (size_t)(m0 + row) * NCOL + col + kbeg;
    lA[j] = c * 8;
  }
  {
    const int c = tid;
    const int row = c >> 2;
    const int col = ((c & 3) ^ ((row >> 2) & 3)) * 8;
    gB = B + (size_t)(e0 + row) * NCOL + col + kbeg;
    lB = c * 8;
  }

  auto issue = [&](int st, int kc) {
#pragma unroll
    for (int j = 0; j < 2; ++j) gl_lds16(gA[j] + kc, &As[st * ASZ + lA[j]]);
    gl_lds16(gB + kc, &Bs[st * BSZ + lB]);
  };

  issue(0, 0);
  int cur = 0;
#pragma unroll 1
  for (int it = 0; it < 64; ++it) {           // BK=32, nk=64
    __builtin_amdgcn_s_barrier();
    if (it < 63) {
      issue(cur ^ 1, (it + 1) * 32);
      __builtin_amdgcn_s_waitcnt(0x0F73);     // my 3 landed; next 3 in flight
    } else {
      __builtin_amdgcn_s_waitcnt(0x0F70);
    }
    __builtin_amdgcn_s_barrier();

    bf16x8 af[4], bfr[2];
#pragma unroll
    for (int mi = 0; mi < 4; ++mi) {
      const int r = wm + mi * 16 + l16;
      af[mi] = *(const bf16x8*)&As[cur * ASZ + r * 32 + ((quad ^ ((r >> 2) & 3)) * 8)];
    }
#pragma unroll
    for (int ni = 0; ni < 2; ++ni) {
      const int r = wn + ni * 16 + l16;
      bfr[ni] = *(const bf16x8*)&Bs[cur * BSZ + r * 32 + ((quad ^ ((r >> 2) & 3)) * 8)];
    }
#pragma unroll
    for (int mi = 0; mi < 4; ++mi)
#pragma unroll
      for (int ni = 0; ni < 2; ++ni)
        acc[mi][ni] = MFMA(af[mi], bfr[ni], acc[mi][ni], 0, 0, 0);
    cur ^= 1;
  }

  unsigned short* Pz = part + (size_t)zt * (8192ull * 512);
#pragma unroll
  for (int mi = 0; mi < 4; ++mi) {
#pragma unroll
    for (int r = 0; r < 4; ++r) {
      const int m = m0 + wm + mi * 16 + quad * 4 + r;
#pragma unroll
      for (int ni = 0; ni < 2; ++ni) {
        const int e = e0 + wn + ni * 16 + l16;
        Pz[(size_t)m * 512 + e] = f2bf(acc[mi][ni][r]);
      }
    }
  }
}

// ================= 128-tile bf16 GEMM (round-0 proven) ====================
// MODE 2: bf16 store of c (small GEMMs). 2-barrier dbuf global_load_lds, BK=64.
template<int MODE, int SWZ, int WM, int WN>
__global__ __launch_bounds__(WM* WN * 64)
void gemm_bt(const unsigned short* __restrict__ A,
             const unsigned short* __restrict__ B,
             void* __restrict__ Cv,
             int M, int N, int K, int KC,
             const float* __restrict__ aux0,
             const float* __restrict__ aux1,
             const float* __restrict__ aux2,
             float* __restrict__ aux3)
{
  constexpr int THREADS = WM * WN * 64;
  constexpr int BMt = WM * 64, BNt = WN * 64;
  constexpr int NA = BMt * 8 / THREADS;
  constexpr int NB = BNt * 8 / THREADS;
  constexpr int L  = NA + NB;
  constexpr int ASZ = BMt * 64, BSZ = BNt * 64;

  __shared__ unsigned short smem[2 * (ASZ + BSZ)];
  unsigned short* As = smem;
  unsigned short* Bs = smem + 2 * ASZ;

  const int tid  = threadIdx.x;
  const int lane = tid & 63;
  const int wv   = tid >> 6;
  const int wm   = (wv / WN) * 64;
  const int wn   = (wv % WN) * 64;
  const int l16  = lane & 15;
  const int quad = lane >> 4;

  const int xt = blockIdx.x, yt = blockIdx.y;
  const int n0 = xt * BNt;
  const int m0 = yt * BMt;

  f32x4 acc[4][4];
#pragma unroll
  for (int i = 0; i < 4; ++i)
#pragma unroll
    for (int j = 0; j < 4; ++j) {
      f32x4 z = {0.f, 0.f, 0.f, 0.f};
      acc[i][j] = z;
    }

  const unsigned short* gA[NA]; int lA[NA];
  const unsigned short* gB[NB]; int lB[NB];
#pragma unroll
  for (int i = 0; i < NA; ++i) {
    const int c = tid + i * THREADS;
    const int row = c >> 3, col = ((c & 7) ^ (row & 7)) * 8;
    gA[i] = A + (size_t)(m0 + row) * K + col;
    lA[i] = c * 8;
  }
#pragma unroll
  for (int i = 0; i < NB; ++i) {
    const int c = tid + i * THREADS;
    const int row = c >> 3, col = ((c & 7) ^ (row & 7)) * 8;
    gB[i] = B + (size_t)(n0 + row) * K + col;
    lB[i] = c * 8;
  }

  auto issue = [&](int st, int kc) {
#pragma unroll
    for (int i = 0; i < NA; ++i) gl_lds16(gA[i] + kc, &As[st * ASZ + lA[i]]);
#pragma unroll
    for (int i = 0; i < NB; ++i) gl_lds16(gB[i] + kc, &Bs[st * BSZ + lB[i]]);
  };

  const int nk = KC >> 6;
  issue(0, 0);

  int cur = 0;
  for (int it = 0; it < nk; ++it) {
    __builtin_amdgcn_s_barrier();
    if (it + 1 < nk) {
      issue(cur ^ 1, (it + 1) << 6);
      __builtin_amdgcn_s_waitcnt(0x0F70 | L);
    } else {
      __builtin_amdgcn_s_waitcnt(0x0F70);
    }
    __builtin_amdgcn_s_barrier();

#pragma unroll
    for (int ks = 0; ks < 2; ++ks) {
      bf16x8 af[4], bfr[4];
#pragma unroll
      for (int mi = 0; mi < 4; ++mi) {
        const int r = wm + mi * 16 + l16;
        af[mi] = *(const bf16x8*)&As[cur * ASZ + r * 64 + (((ks * 4 + quad) ^ (r & 7)) * 8)];
      }
#pragma unroll
      for (int ni = 0; ni < 4; ++ni) {
        const int r = wn + ni * 16 + l16;
        bfr[ni] = *(const bf16x8*)&Bs[cur * BSZ + r * 64 + (((ks * 4 + quad) ^ (r & 7)) * 8)];
      }
#pragma unroll
      for (int mi = 0; mi < 4; ++mi)
#pragma unroll
        for (int ni = 0; ni < 4; ++ni)
          acc[mi][ni] = MFMA(af[mi], bfr[ni], acc[mi][ni], 0, 0, 0);
    }
    cur ^= 1;
  }

  unsigned short* Pz = (unsigned short*)Cv;
#pragma unroll
  for (int mi = 0; mi < 4; ++mi) {
#pragma unroll
    for (int r = 0; r < 4; ++r) {
      const int m = m0 + wm + mi * 16 + quad * 4 + r;
#pragma unroll
      for (int ni = 0; ni < 4; ++ni) {
        const int n = n0 + wn + ni * 16 + l16;
        Pz[(size_t)m * N + n] = f2bf(acc[mi][ni][r]);
      }
    }
  }
  (void)aux0; (void)aux1; (void)aux2; (void)aux3;
}

// ===== prep_all: conversions/norms/bias in ONE launch (3456 blocks) =====
// [0,2048): x rows -> xq(fp8), x2, denom=0 ; [2048,3072): p -> pq(fp8), pb, p2 ;
// [3072,3328): wv,wo -> bf16 ; [3328,3456): bias2
__global__ void prep_all(const float* __restrict__ x, const float* __restrict__ positions,
                         const float* __restrict__ w_v, const float* __restrict__ w_o,
                         const float* __restrict__ b_v, const float* __restrict__ b_o,
                         unsigned char* __restrict__ xq, unsigned char* __restrict__ pq,
                         unsigned short* __restrict__ pb,
                         unsigned short* __restrict__ wvb, unsigned short* __restrict__ wob,
                         float* __restrict__ x2, float* __restrict__ p2,
                         float* __restrict__ bias2, float* __restrict__ denom)
{
  const int b = blockIdx.x;
  const int tid = threadIdx.x;
  const int lane = tid & 63;
  const int wv = tid >> 6;

  if (b < 3072) {
    const bool isx = (b < 2048);
    const int r = (isx ? b : b - 2048) * 4 + wv;
    const float* X = isx ? x : positions;
    const float4* row = (const float4*)(X + (size_t)r * 512);
    const float4 a = row[lane];
    const float4 c = row[lane + 64];
    // fp8 e4m3 pack (RNE, saturating); no scaling needed (|x|<~6, |p|<~0.6)
    int wa = __builtin_amdgcn_cvt_pk_fp8_f32(a.x, a.y, 0, false);
    wa = __builtin_amdgcn_cvt_pk_fp8_f32(a.z, a.w, wa, true);
    int wc = __builtin_amdgcn_cvt_pk_fp8_f32(c.x, c.y, 0, false);
    wc = __builtin_amdgcn_cvt_pk_fp8_f32(c.z, c.w, wc, true);
    unsigned int* Q = (unsigned int*)(isx ? xq : pq) + (size_t)r * 128;
    Q[lane] = (unsigned int)wa;
    Q[lane + 64] = (unsigned int)wc;
    if (!isx) {                               // bf16 p kept for the val-GEMM
      ushort4 ua, uc;
      ua.x = f2bf(a.x); ua.y = f2bf(a.y); ua.z = f2bf(a.z); ua.w = f2bf(a.w);
      uc.x = f2bf(c.x); uc.y = f2bf(c.y); uc.z = f2bf(c.z); uc.w = f2bf(c.w);
      ushort4* orow = (ushort4*)(pb + (size_t)r * 512);
      orow[lane] = ua;
      orow[lane + 64] = uc;
    }
    float s = a.x*a.x + a.y*a.y + a.z*a.z + a.w*a.w
            + c.x*c.x + c.y*c.y + c.z*c.z + c.w*c.w;
#pragma unroll
    for (int off = 32; off > 0; off >>= 1) s += __shfl_down(s, off, 64);
    if (lane == 0) {
      if (isx) { x2[r] = s; denom[r] = 0.f; }
      else     { p2[r] = s; }
    }
  } else if (b < 3328) {
    const int i = (b - 3072) * 256 + tid;   // 65536 float4 each
    float4 a = ((const float4*)w_v)[i];
    float4 c = ((const float4*)w_o)[i];
    ushort4 ua, uc;
    ua.x = f2bf(a.x); ua.y = f2bf(a.y); ua.z = f2bf(a.z); ua.w = f2bf(a.w);
    uc.x = f2bf(c.x); uc.y = f2bf(c.y); uc.z = f2bf(c.z); uc.w = f2bf(c.w);
    ((ushort4*)wvb)[i] = ua;
    ((ushort4*)wob)[i] = uc;
  } else {
    const int e = (b - 3328) * 4 + wv;
    float s = 0.f;
#pragma unroll
    for (int j = 0; j < 8; ++j)
      s += w_o[(size_t)e * 512 + lane + j * 64] * b_v[lane + j * 64];
#pragma unroll
    for (int off = 32; off > 0; off >>= 1) s += __shfl_down(s, off, 64);
    if (lane == 0) bias2[e] = b_o[e] + s;   // softmax rows sum to 1
  }
}

// out[m,e] = (P0[m,e] + P1[m,e]) / denom[m] + bias2[e]   (P bf16, out fp32)
__global__ void reduce_out(const unsigned short* __restrict__ P,
                           const float* __restrict__ denom,
                           const float* __restrict__ bias2,
                           float* __restrict__ out) {
  const int i = blockIdx.x * 256 + threadIdx.x;   // 1,048,576 float4s
  const int m = i >> 7;
  const float rd = 1.0f / denom[m];
  const float4 b4 = ((const float4*)bias2)[i & 127];
  const ushort4 p0 = ((const ushort4*)P)[i];
  const ushort4 p1 = ((const ushort4*)P)[i + 1048576];
  float4 o;
  o.x = (bf2f(p0.x) + bf2f(p1.x)) * rd + b4.x;
  o.y = (bf2f(p0.y) + bf2f(p1.y)) * rd + b4.y;
  o.z = (bf2f(p0.z) + bf2f(p1.z)) * rd + b4.z;
  o.w = (bf2f(p0.w) + bf2f(p1.w)) * rd + b4.w;
  ((float4*)out)[i] = o;
}

extern "C" void kernel_launch(void* const* d_in, const int* in_sizes, int n_in,
                              void* d_out, int out_size, void* d_ws, size_t ws_size,
                              hipStream_t stream) {
  const float* x         = (const float*)d_in[0];
  const float* positions = (const float*)d_in[1];
  const float* scale     = (const float*)d_in[2];
  const float* w_v       = (const float*)d_in[3];
  const float* b_v       = (const float*)d_in[4];
  const float* w_o       = (const float*)d_in[5];
  const float* b_o       = (const float*)d_in[6];
  float* out = (float*)d_out;

  char* base = (char*)d_ws;
  unsigned short* Eb    = (unsigned short*)(base + 0);          // 64 MB [E .. PV]
  unsigned short* val   = (unsigned short*)(base + 0);          // 4 MB, parks in Eb
  unsigned short* v2T   = (unsigned short*)(base + 67108864);   // 4 MB
  float*          denom = (float*)(base + 71303168);            // 32 KB
  float*          x2    = (float*)(base + 71335936);            // 32 KB
  float*          p2    = (float*)(base + 71368704);            // 16 KB
  float*          bias2 = (float*)(base + 71385088);            // 2 KB
  char* base2 = base + 71387136;
  unsigned short* part  = (unsigned short*)base2;               // 16 MB [PV .. reduce]
  unsigned char*  xq    = (unsigned char*)base2;                // 4 MB  [prep .. E]
  unsigned char*  pq    = (unsigned char*)(base2 + 4194304);    // 2 MB  [prep .. E]
  unsigned short* pb    = (unsigned short*)(base2 + 6291456);   // 4 MB  [prep .. val]
  unsigned short* wvb   = (unsigned short*)(base2 + 10485760);  // 0.5 MB
  unsigned short* wo_b  = (unsigned short*)(base2 + 11010048);  // 0.5 MB

  // all prep in one launch
  prep_all<<<3456, 256, 0, stream>>>(x, positions, w_v, w_o, b_v, b_o,
                                     xq, pq, pb, wvb, wo_b, x2, p2, bias2, denom);

  // val[n,d] = sum_k p[n,k] wv[d,k]
  gemm_bt<2, 0, 2, 2><<<dim3(4, 32), 256, 0, stream>>>(
      pb, wvb, val, 4096, 512, 512, 512, nullptr, nullptr, nullptr, nullptr);

  // v2T[e,n] = sum_d wo[e,d] val[n,d]
  gemm_bt<2, 0, 2, 2><<<dim3(32, 4), 256, 0, stream>>>(
      wo_b, val, v2T, 512, 4096, 512, 512, nullptr, nullptr, nullptr, nullptr);

  // E[m,n] = exp(scale[n]/(dist+0.1)); denom[m] += row sums
  // fp8, BK=64, 34.8KB LDS -> 4 blocks/CU
  gemm_f8<<<2048, 256, 0, stream>>>(xq, pq, Eb, x2, p2, scale, denom);

  // part[z][m,e] = sum_{n in half z} E[m,n] v2T[e,n]
  // 128x64x32 tiles, 24KB LDS -> 4 blocks/CU
  gemm_pv<<<1024, 256, 0, stream>>>(Eb, v2T, part);

  // out = (part0 + part1)/denom + bias2
  reduce_out<<<4096, 256, 0, stream>>>(part, denom, bias2, out);
}

// Round 7
// 203.560 us; speedup vs baseline: 1.0280x; 1.0280x over previous
//
#include <hip/hip_runtime.h>
#include <cstdint>
#include <cstddef>

using bf16x8 = __attribute__((ext_vector_type(8))) short;
using f32x4  = __attribute__((ext_vector_type(4))) float;

__device__ __forceinline__ unsigned short f2bf(float f) {
  unsigned int u = __builtin_bit_cast(unsigned int, f);
  u += 0x7FFFu + ((u >> 16) & 1u);   // round-to-nearest-even
  return (unsigned short)(u >> 16);
}
__device__ __forceinline__ float bf2f(unsigned int h16) {
  unsigned int u = h16 << 16;
  return __builtin_bit_cast(float, u);
}

__device__ __forceinline__ void gl_lds16(const void* g, void* l) {
  __builtin_amdgcn_global_load_lds(
      (const __attribute__((address_space(1))) unsigned int*)g,
      (__attribute__((address_space(3))) unsigned int*)l,
      16, 0, 0);
}

#define MFMA  __builtin_amdgcn_mfma_f32_16x16x32_bf16
#define MFMA8 __builtin_amdgcn_mfma_f32_16x16x32_fp8_fp8

// ============ fp8 E-kernel: E[m,n]=exp(scale/(dist+0.1)), denom atomics ====
// R6 structure (BK=64 fp8, proven fragments/epilogue) + the one untested
// lever: 3-slot DISTANCE-2 staging with COUNTED vmcnt at 3 blocks/CU.
// step t: issue(slot[(t+2)%3])  [that slot's readers finished at t-1 barrier]
//         compute slot[t%3]     [32 fp8 MFMA]
//         vmcnt(4)              [t+1's 4 loads landed; t+2's stay in flight
//                                ACROSS the barrier -- T4, never drain to 0]
//         barrier
// Prior distance-2 tests (R2/R4) were at 1-2 blocks/CU where nothing hides;
// this is the first at bpc>=3.
__global__ __launch_bounds__(256, 3)
void gemm_f8(const unsigned char* __restrict__ A,   // [8192][512] fp8 e4m3
             const unsigned char* __restrict__ B,   // [4096][512] fp8 e4m3
             unsigned short* __restrict__ Eg,       // [8192][4096] bf16
             const float* __restrict__ x2g,
             const float* __restrict__ p2g,
             const float* __restrict__ scg,
             float* __restrict__ denom)
{
  constexpr int K = 512, N = 4096;
  constexpr int SLOT = 16384;                 // bytes: A 8KB + B 8KB
  __shared__ unsigned char smem[3 * SLOT];    // 48 KB -> 3 blocks/CU
                                              // (epilogue 34.8KB tile overlays)
  const int tid  = threadIdx.x;
  const int lane = tid & 63;
  const int wv   = tid >> 6;
  const int wm   = (wv >> 1) * 64;
  const int wn   = (wv & 1) * 64;
  const int l16  = lane & 15;
  const int quad = lane >> 4;

  // 2048 blocks: XCD owns a 4-wide n-band (p-slice L2-resident per XCD)
  const int lin = blockIdx.x;
  const int xcd = lin & 7, per = lin >> 3;
  const int xt = xcd * 4 + (per & 3), yt = per >> 2;
  const int n0 = xt * 128, m0 = yt * 128;

  f32x4 acc[4][4];
#pragma unroll
  for (int i = 0; i < 4; ++i)
#pragma unroll
    for (int j = 0; j < 4; ++j) {
      f32x4 z = {0.f, 0.f, 0.f, 0.f};
      acc[i][j] = z;
    }

  // staging: c = tid + i*256 in [0,512): row=c>>2, slot chunk q=c&3,
  // global chunk = q ^ ((row>>2)&3)   (64-B rows, proven in R6)
  const unsigned char* gA[2]; const unsigned char* gB[2]; int lA[2];
#pragma unroll
  for (int i = 0; i < 2; ++i) {
    const int c = tid + i * 256;
    const int row = c >> 2;
    const int colb = ((c & 3) ^ ((row >> 2) & 3)) * 16;
    gA[i] = A + (size_t)(m0 + row) * K + colb;
    gB[i] = B + (size_t)(n0 + row) * K + colb;
    lA[i] = c * 16;
  }

  auto issue = [&](int sl, int kc) {
    unsigned char* S = smem + sl * SLOT;
#pragma unroll
    for (int i = 0; i < 2; ++i) gl_lds16(gA[i] + kc, &S[lA[i]]);
#pragma unroll
    for (int i = 0; i < 2; ++i) gl_lds16(gB[i] + kc, &S[8192 + lA[i]]);
  };

  auto compute = [&](int sl) {
    const unsigned char* As = smem + sl * SLOT;
    const unsigned char* Bs = As + 8192;
    __builtin_amdgcn_s_setprio(1);
#pragma unroll
    for (int sub = 0; sub < 2; ++sub) {       // 2 x K=32 sub-steps
      long af[4], bq[4];
#pragma unroll
      for (int mi = 0; mi < 4; ++mi) {
        const int r = wm + mi * 16 + l16;
        af[mi] = *(const long*)&As[r * 64 +
                   (((sub * 2 + (quad >> 1)) ^ ((r >> 2) & 3)) * 16) + (quad & 1) * 8];
      }
#pragma unroll
      for (int ni = 0; ni < 4; ++ni) {
        const int r = wn + ni * 16 + l16;
        bq[ni] = *(const long*)&Bs[r * 64 +
                   (((sub * 2 + (quad >> 1)) ^ ((r >> 2) & 3)) * 16) + (quad & 1) * 8];
      }
#pragma unroll
      for (int mi = 0; mi < 4; ++mi)
#pragma unroll
        for (int ni = 0; ni < 4; ++ni)
          acc[mi][ni] = MFMA8(af[mi], bq[ni], acc[mi][ni], 0, 0, 0);
    }
    __builtin_amdgcn_s_setprio(0);
  };

  // prologue: steps 0,1 in flight; wait step0 only (vmcnt 4)
  issue(0, 0);
  issue(1, 64);
  __builtin_amdgcn_s_waitcnt(0x0F74);
  __builtin_amdgcn_s_barrier();

  int s0 = 0, s1 = 1, s2 = 2;
#pragma unroll 1
  for (int it = 0; it < 8; ++it) {            // BK=64, nk=8
    if (it + 2 < 8) issue(s2, (it + 2) * 64); // distance-2 prefetch
    compute(s0);
    if (it + 2 < 8) __builtin_amdgcn_s_waitcnt(0x0F74);  // t+1 landed; t+2 flying
    else            __builtin_amdgcn_s_waitcnt(0x0F70);  // tail drain
    __builtin_amdgcn_s_barrier();
    const int t = s0; s0 = s1; s1 = s2; s2 = t;
  }

  // ---- epilogue (proven): exp into 136-stride LDS tile, row sums, stores ----
  float p2v[4], scv[4];
#pragma unroll
  for (int ni = 0; ni < 4; ++ni) {
    const int n = n0 + wn + ni * 16 + l16;
    p2v[ni] = p2g[n];
    scv[ni] = scg[n] * 1.44269504088896f;     // fold log2(e)
  }
  __syncthreads();                            // done with K-loop LDS
  unsigned short* Es = (unsigned short*)smem; // 128 x (136-stride) bf16 tile
#pragma unroll
  for (int mi = 0; mi < 4; ++mi) {
#pragma unroll
    for (int r = 0; r < 4; ++r) {
      const int rowL = wm + mi * 16 + quad * 4 + r;
      const float rowa = x2g[m0 + rowL];
      float s = 0.f;
#pragma unroll
      for (int ni = 0; ni < 4; ++ni) {
        const int col = wn + ni * 16 + l16;
        const float v = acc[mi][ni][r];
        float sq   = fmaxf(rowa - 2.0f * v + p2v[ni], 0.0f);
        float dist = __builtin_amdgcn_sqrtf(sq);
        float e    = __builtin_amdgcn_exp2f(scv[ni] * __builtin_amdgcn_rcpf(dist + 0.1f));
        Es[rowL * 136 + col] = f2bf(e);
        s += e;                               // unrounded sum (rel err ~3e-5)
      }
      s += __shfl_down(s, 8);
      s += __shfl_down(s, 4);
      s += __shfl_down(s, 2);
      s += __shfl_down(s, 1);
      if (l16 == 0) unsafeAtomicAdd(&denom[m0 + rowL], s);
    }
  }
  __syncthreads();
#pragma unroll
  for (int j = 0; j < 8; ++j) {               // coalesced 16B stores
    const int cid = j * 256 + tid;
    const int row = cid >> 4, cc = cid & 15;
    bf16x8 v = *(const bf16x8*)&Es[row * 136 + cc * 8];
    *(bf16x8*)&Eg[(size_t)(m0 + row) * N + n0 + cc * 8] = v;
  }
}

// ============ PV kernel: part[z][m,e] = sum_{n in half z} E[m,n] v2T[e,n] ===
// R6's thin-step version (BK=32, nk=64, 8 MFMA/step, 6.3M bank conflicts) was
// null vs R0. This one: FAT steps at 3 blocks/CU -- BM=128, BN(e)=64, BK=64
// (128B rows, the R0-proven chunk-XOR q^(r&7), ~free), 48KB LDS, nk=32,
// 16 MFMA/step/wave. Grid 1024 (64m x 8e x 2z), m-octet pinned per XCD
// (E slices L3-resident; v2T e-slice L2-resident).
__global__ __launch_bounds__(256, 3)
void gemm_pv(const unsigned short* __restrict__ A,   // E: [8192][4096] bf16
             const unsigned short* __restrict__ B,   // v2T: [512][4096] bf16
             unsigned short* __restrict__ part)      // [2][8192][512] bf16
{
  constexpr int NCOL = 4096, KC = 2048;
  constexpr int ASZ = 128 * 64;   // shorts per A slot (16 KB)
  constexpr int BSZ = 64 * 64;    // shorts per B slot (8 KB)
  __shared__ unsigned short smem[2 * (ASZ + BSZ)];   // 48 KB
  unsigned short* As = smem;
  unsigned short* Bs = smem + 2 * ASZ;

  const int tid  = threadIdx.x;
  const int lane = tid & 63;
  const int wv   = tid >> 6;
  const int l16  = lane & 15;
  const int quad = lane >> 4;
  const int wm   = (wv >> 1) * 64;   // 2 m-waves
  const int wn   = (wv & 1) * 32;    // 2 e-waves

  const int lin = blockIdx.x;                 // 1024 blocks
  const int xcd = lin & 7, i = lin >> 3;      // i in [0,128)
  const int yt  = xcd * 8 + (i & 7);          // m-tile octet pinned to XCD
  const int combo = i >> 3;                   // 0..15
  const int et  = combo & 7;                  // e-tile (8 x 64)
  const int zt  = combo >> 3;                 // K half
  const int m0  = yt * 128;
  const int e0  = et * 64;
  const int kbeg = zt * KC;

  f32x4 acc[4][2];
#pragma unroll
  for (int a = 0; a < 4; ++a)
#pragma unroll
    for (int b = 0; b < 2; ++b) {
      f32x4 z = {0.f, 0.f, 0.f, 0.f};
      acc[a][b] = z;
    }

  // staging (128B rows = 8 chunks of 16B; chunk q of row r at q^(r&7)):
  // A: c = tid + i*256 in [0,1024): row=c>>3 (0..127)
  // B: c = tid + i*256 in [0,512):  row=c>>3 (0..63)
  const unsigned short* gA[4]; int lA[4];
  const unsigned short* gB[2]; int lB[2];
#pragma unroll
  for (int j = 0; j < 4; ++j) {
    const int c = tid + j * 256;
    const int row = c >> 3, col = ((c & 7) ^ (row & 7)) * 8;
    gA[j] = A + (size_t)(m0 + row) * NCOL + col + kbeg;
    lA[j] = c * 8;
  }
#pragma unroll
  for (int j = 0; j < 2; ++j) {
    const int c = tid + j * 256;
    const int row = c >> 3, col = ((c & 7) ^ (row & 7)) * 8;
    gB[j] = B + (size_t)(e0 + row) * NCOL + col + kbeg;
    lB[j] = c * 8;
  }

  auto issue = [&](int st, int kc) {
#pragma unroll
    for (int j = 0; j < 4; ++j) gl_lds16(gA[j] + kc, &As[st * ASZ + lA[j]]);
#pragma unroll
    for (int j = 0; j < 2; ++j) gl_lds16(gB[j] + kc, &Bs[st * BSZ + lB[j]]);
  };

  issue(0, 0);
  int cur = 0;
#pragma unroll 1
  for (int it = 0; it < 32; ++it) {           // BK=64, nk=32
    __builtin_amdgcn_s_barrier();
    if (it < 31) {
      issue(cur ^ 1, (it + 1) * 64);
      __builtin_amdgcn_s_waitcnt(0x0F76);     // my 6 landed; next 6 in flight
    } else {
      __builtin_amdgcn_s_waitcnt(0x0F70);
    }
    __builtin_amdgcn_s_barrier();

    __builtin_amdgcn_s_setprio(1);
#pragma unroll
    for (int ks = 0; ks < 2; ++ks) {
      bf16x8 af[4], bfr[2];
#pragma unroll
      for (int mi = 0; mi < 4; ++mi) {
        const int r = wm + mi * 16 + l16;
        af[mi] = *(const bf16x8*)&As[cur * ASZ + r * 64 + (((ks * 4 + quad) ^ (r & 7)) * 8)];
      }
#pragma unroll
      for (int ni = 0; ni < 2; ++ni) {
        const int r = wn + ni * 16 + l16;
        bfr[ni] = *(const bf16x8*)&Bs[cur * BSZ + r * 64 + (((ks * 4 + quad) ^ (r & 7)) * 8)];
      }
#pragma unroll
      for (int mi = 0; mi < 4; ++mi)
#pragma unroll
        for (int ni = 0; ni < 2; ++ni)
          acc[mi][ni] = MFMA(af[mi], bfr[ni], acc[mi][ni], 0, 0, 0);
    }
    __builtin_amdgcn_s_setprio(0);
    cur ^= 1;
  }

  unsigned short* Pz = part + (size_t)zt * (8192ull * 512);
#pragma unroll
  for (int mi = 0; mi < 4; ++mi) {
#pragma unroll
    for (int r = 0; r < 4; ++r) {
      const int m = m0 + wm + mi * 16 + quad * 4 + r;
#pragma unroll
      for (int ni = 0; ni < 2; ++ni) {
        const int e = e0 + wn + ni * 16 + l16;
        Pz[(size_t)m * 512 + e] = f2bf(acc[mi][ni][r]);
      }
    }
  }
}

// ============ 64x64-tile GEMM for the two small 512-K GEMMs ================
// The 128-tile version ran 128-block grids (half the GPU idle, latency-bound,
// ~25us each). 64^2 tiles -> 512 blocks, 32KB LDS, nk=8.
// C[m,n] = sum_k A[m,k]*B[n,k]; 4 waves, wave w owns n-cols [16w,16w+16).
__global__ __launch_bounds__(256, 4)
void gemm64(const unsigned short* __restrict__ A,
            const unsigned short* __restrict__ B,
            unsigned short* __restrict__ C,
            int M, int N, int K)
{
  constexpr int ASZ = 64 * 64;    // shorts per slot (8 KB)
  __shared__ unsigned short smem[4 * ASZ];    // A0 A1 B0 B1 = 32 KB
  unsigned short* As = smem;
  unsigned short* Bs = smem + 2 * ASZ;

  const int tid  = threadIdx.x;
  const int lane = tid & 63;
  const int wv   = tid >> 6;
  const int l16  = lane & 15;
  const int quad = lane >> 4;

  const int n0 = blockIdx.x * 64;
  const int m0 = blockIdx.y * 64;

  f32x4 acc[4];
#pragma unroll
  for (int i = 0; i < 4; ++i) {
    f32x4 z = {0.f, 0.f, 0.f, 0.f};
    acc[i] = z;
  }

  // staging: c = tid + i*256 in [0,512): row=c>>3 (0..63), chunk q=c&7 at q^(r&7)
  const unsigned short* gA[2]; const unsigned short* gB[2]; int lc[2];
#pragma unroll
  for (int i = 0; i < 2; ++i) {
    const int c = tid + i * 256;
    const int row = c >> 3, col = ((c & 7) ^ (row & 7)) * 8;
    gA[i] = A + (size_t)(m0 + row) * K + col;
    gB[i] = B + (size_t)(n0 + row) * K + col;
    lc[i] = c * 8;
  }

  auto issue = [&](int st, int kc) {
#pragma unroll
    for (int i = 0; i < 2; ++i) gl_lds16(gA[i] + kc, &As[st * ASZ + lc[i]]);
#pragma unroll
    for (int i = 0; i < 2; ++i) gl_lds16(gB[i] + kc, &Bs[st * ASZ + lc[i]]);
  };

  const int nk = K >> 6;
  issue(0, 0);
  int cur = 0;
#pragma unroll 1
  for (int it = 0; it < nk; ++it) {
    __builtin_amdgcn_s_barrier();
    if (it + 1 < nk) {
      issue(cur ^ 1, (it + 1) << 6);
      __builtin_amdgcn_s_waitcnt(0x0F74);     // my 4 landed; next 4 in flight
    } else {
      __builtin_amdgcn_s_waitcnt(0x0F70);
    }
    __builtin_amdgcn_s_barrier();

#pragma unroll
    for (int ks = 0; ks < 2; ++ks) {
      bf16x8 af[4], bfr;
#pragma unroll
      for (int mi = 0; mi < 4; ++mi) {
        const int r = mi * 16 + l16;
        af[mi] = *(const bf16x8*)&As[cur * ASZ + r * 64 + (((ks * 4 + quad) ^ (r & 7)) * 8)];
      }
      {
        const int r = wv * 16 + l16;
        bfr = *(const bf16x8*)&Bs[cur * ASZ + r * 64 + (((ks * 4 + quad) ^ (r & 7)) * 8)];
      }
#pragma unroll
      for (int mi = 0; mi < 4; ++mi)
        acc[mi] = MFMA(af[mi], bfr, acc[mi], 0, 0, 0);
    }
    cur ^= 1;
  }

#pragma unroll
  for (int mi = 0; mi < 4; ++mi) {
#pragma unroll
    for (int r = 0; r < 4; ++r) {
      const int m = m0 + mi * 16 + quad * 4 + r;
      const int n = n0 + wv * 16 + l16;
      C[(size_t)m * N + n] = f2bf(acc[mi][r]);
    }
  }
}

// ===== prep_all: conversions/norms/bias in ONE launch (3456 blocks) =====
// [0,2048): x rows -> xq(fp8), x2, denom=0 ; [2048,3072): p -> pq(fp8), pb, p2 ;
// [3072,3328): wv,wo -> bf16 ; [3328,3456): bias2
__global__ void prep_all(const float* __restrict__ x, const float* __restrict__ positions,
                         const float* __restrict__ w_v, const float* __restrict__ w_o,
                         const float* __restrict__ b_v, const float* __restrict__ b_o,
                         unsigned char* __restrict__ xq, unsigned char* __restrict__ pq,
                         unsigned short* __restrict__ pb,
                         unsigned short* __restrict__ wvb, unsigned short* __restrict__ wob,
                         float* __restrict__ x2, float* __restrict__ p2,
                         float* __restrict__ bias2, float* __restrict__ denom)
{
  const int b = blockIdx.x;
  const int tid = threadIdx.x;
  const int lane = tid & 63;
  const int wv = tid >> 6;

  if (b < 3072) {
    const bool isx = (b < 2048);
    const int r = (isx ? b : b - 2048) * 4 + wv;
    const float* X = isx ? x : positions;
    const float4* row = (const float4*)(X + (size_t)r * 512);
    const float4 a = row[lane];
    const float4 c = row[lane + 64];
    // fp8 e4m3 pack (RNE, saturating); no scaling needed (|x|<~6, |p|<~0.6)
    int wa = __builtin_amdgcn_cvt_pk_fp8_f32(a.x, a.y, 0, false);
    wa = __builtin_amdgcn_cvt_pk_fp8_f32(a.z, a.w, wa, true);
    int wc = __builtin_amdgcn_cvt_pk_fp8_f32(c.x, c.y, 0, false);
    wc = __builtin_amdgcn_cvt_pk_fp8_f32(c.z, c.w, wc, true);
    unsigned int* Q = (unsigned int*)(isx ? xq : pq) + (size_t)r * 128;
    Q[lane] = (unsigned int)wa;
    Q[lane + 64] = (unsigned int)wc;
    if (!isx) {                               // bf16 p kept for the val-GEMM
      ushort4 ua, uc;
      ua.x = f2bf(a.x); ua.y = f2bf(a.y); ua.z = f2bf(a.z); ua.w = f2bf(a.w);
      uc.x = f2bf(c.x); uc.y = f2bf(c.y); uc.z = f2bf(c.z); uc.w = f2bf(c.w);
      ushort4* orow = (ushort4*)(pb + (size_t)r * 512);
      orow[lane] = ua;
      orow[lane + 64] = uc;
    }
    float s = a.x*a.x + a.y*a.y + a.z*a.z + a.w*a.w
            + c.x*c.x + c.y*c.y + c.z*c.z + c.w*c.w;
#pragma unroll
    for (int off = 32; off > 0; off >>= 1) s += __shfl_down(s, off, 64);
    if (lane == 0) {
      if (isx) { x2[r] = s; denom[r] = 0.f; }
      else     { p2[r] = s; }
    }
  } else if (b < 3328) {
    const int i = (b - 3072) * 256 + tid;   // 65536 float4 each
    float4 a = ((const float4*)w_v)[i];
    float4 c = ((const float4*)w_o)[i];
    ushort4 ua, uc;
    ua.x = f2bf(a.x); ua.y = f2bf(a.y); ua.z = f2bf(a.z); ua.w = f2bf(a.w);
    uc.x = f2bf(c.x); uc.y = f2bf(c.y); uc.z = f2bf(c.z); uc.w = f2bf(c.w);
    ((ushort4*)wvb)[i] = ua;
    ((ushort4*)wob)[i] = uc;
  } else {
    const int e = (b - 3328) * 4 + wv;
    float s = 0.f;
#pragma unroll
    for (int j = 0; j < 8; ++j)
      s += w_o[(size_t)e * 512 + lane + j * 64] * b_v[lane + j * 64];
#pragma unroll
    for (int off = 32; off > 0; off >>= 1) s += __shfl_down(s, off, 64);
    if (lane == 0) bias2[e] = b_o[e] + s;   // softmax rows sum to 1
  }
}

// out[m,e] = (P0[m,e] + P1[m,e]) / denom[m] + bias2[e]   (P bf16, out fp32)
__global__ void reduce_out(const unsigned short* __restrict__ P,
                           const float* __restrict__ denom,
                           const float* __restrict__ bias2,
                           float* __restrict__ out) {
  const int i = blockIdx.x * 256 + threadIdx.x;   // 1,048,576 float4s
  const int m = i >> 7;
  const float rd = 1.0f / denom[m];
  const float4 b4 = ((const float4*)bias2)[i & 127];
  const ushort4 p0 = ((const ushort4*)P)[i];
  const ushort4 p1 = ((const ushort4*)P)[i + 1048576];
  float4 o;
  o.x = (bf2f(p0.x) + bf2f(p1.x)) * rd + b4.x;
  o.y = (bf2f(p0.y) + bf2f(p1.y)) * rd + b4.y;
  o.z = (bf2f(p0.z) + bf2f(p1.z)) * rd + b4.z;
  o.w = (bf2f(p0.w) + bf2f(p1.w)) * rd + b4.w;
  ((float4*)out)[i] = o;
}

extern "C" void kernel_launch(void* const* d_in, const int* in_sizes, int n_in,
                              void* d_out, int out_size, void* d_ws, size_t ws_size,
                              hipStream_t stream) {
  const float* x         = (const float*)d_in[0];
  const float* positions = (const float*)d_in[1];
  const float* scale     = (const float*)d_in[2];
  const float* w_v       = (const float*)d_in[3];
  const float* b_v       = (const float*)d_in[4];
  const float* w_o       = (const float*)d_in[5];
  const float* b_o       = (const float*)d_in[6];
  float* out = (float*)d_out;

  char* base = (char*)d_ws;
  unsigned short* Eb    = (unsigned short*)(base + 0);          // 64 MB [E .. PV]
  unsigned short* val   = (unsigned short*)(base + 0);          // 4 MB, parks in Eb
  unsigned short* v2T   = (unsigned short*)(base + 67108864);   // 4 MB
  float*          denom = (float*)(base + 71303168);            // 32 KB
  float*          x2    = (float*)(base + 71335936);            // 32 KB
  float*          p2    = (float*)(base + 71368704);            // 16 KB
  float*          bias2 = (float*)(base + 71385088);            // 2 KB
  char* base2 = base + 71387136;
  unsigned short* part  = (unsigned short*)base2;               // 16 MB [PV .. reduce]
  unsigned char*  xq    = (unsigned char*)base2;                // 4 MB  [prep .. E]
  unsigned char*  pq    = (unsigned char*)(base2 + 4194304);    // 2 MB  [prep .. E]
  unsigned short* pb    = (unsigned short*)(base2 + 6291456);   // 4 MB  [prep .. val]
  unsigned short* wvb   = (unsigned short*)(base2 + 10485760);  // 0.5 MB
  unsigned short* wo_b  = (unsigned short*)(base2 + 11010048);  // 0.5 MB

  // all prep in one launch
  prep_all<<<3456, 256, 0, stream>>>(x, positions, w_v, w_o, b_v, b_o,
                                     xq, pq, pb, wvb, wo_b, x2, p2, bias2, denom);

  // val[n,d] = sum_k p[n,k] wv[d,k]   (512 blocks of 64x64)
  gemm64<<<dim3(8, 64), 256, 0, stream>>>(pb, wvb, val, 4096, 512, 512);

  // v2T[e,n] = sum_d wo[e,d] val[n,d]   (512 blocks of 64x64)
  gemm64<<<dim3(64, 8), 256, 0, stream>>>(wo_b, val, v2T, 512, 4096, 512);

  // E[m,n] = exp(scale[n]/(dist+0.1)); denom[m] += row sums
  // fp8 BK=64, 3-slot distance-2 counted vmcnt, 48KB -> 3 blocks/CU
  gemm_f8<<<2048, 256, 0, stream>>>(xq, pq, Eb, x2, p2, scale, denom);

  // part[z][m,e] = sum_{n in half z} E[m,n] v2T[e,n]
  // 128x64x64 fat steps, 48KB -> 3 blocks/CU
  gemm_pv<<<1024, 256, 0, stream>>>(Eb, v2T, part);

  // out = (part0 + part1)/denom + bias2
  reduce_out<<<4096, 256, 0, stream>>>(part, denom, bias2, out);
}